// Round 6
// baseline (505.153 us; speedup 1.0000x reference)
//
#include <hip/hip_runtime.h>

#define DIM   1024
#define NHEAD 16
#define HD    64
#define SEQ   2048
#define BATCH 2
#define MROWS (BATCH * SEQ)   // 4096
#define NT    (SEQ / 64)      // 32 KV tiles

typedef __attribute__((ext_vector_type(8))) _Float16 s8h;   // 8 f16 in 4 VGPRs
typedef __attribute__((ext_vector_type(4))) _Float16 s4h;   // 4 f16 (8B)
typedef __attribute__((ext_vector_type(4))) float f32x4;

typedef const __attribute__((address_space(1))) unsigned GU;
typedef __attribute__((address_space(3))) unsigned LU;

__device__ __forceinline__ void gll16(const void* g, void* l) {
    // async global->LDS, 16B/lane; LDS dest = wave-uniform base + lane*16
    __builtin_amdgcn_global_load_lds((GU*)g, (LU*)l, 16, 0, 0);
}
__device__ __forceinline__ f32x4 mfma16(s8h a, s8h b, f32x4 c) {
    return __builtin_amdgcn_mfma_f32_16x16x32_f16(a, b, c, 0, 0, 0);
}
// 2^x via v_exp_f32. NOTE: not named __exp2f (glibc owns that symbol).
__device__ __forceinline__ float ex2(float x) {
    return __builtin_amdgcn_exp2f(x);
}

// ---------------- fp32 -> fp16 cast: x | Wq | Wk | Wv | Wo ----------------
__global__ __launch_bounds__(256) void cast_f16_kernel(
    const float* __restrict__ x,  const float* __restrict__ wq,
    const float* __restrict__ wk, const float* __restrict__ wv,
    const float* __restrict__ wo,
    _Float16* __restrict__ xh,  _Float16* __restrict__ wqh,
    _Float16* __restrict__ wkh, _Float16* __restrict__ wvh,
    _Float16* __restrict__ woh) {
    int id = blockIdx.x * 256 + threadIdx.x;   // 1,048,576 threads x 8 elems
    const float* src; _Float16* dst; size_t off;
    if (id < 524288) { src = x; dst = xh; off = (size_t)id * 8; }
    else {
        int r = id - 524288, w = r >> 17, o = r & 131071;
        src = (w == 0) ? wq : (w == 1) ? wk : (w == 2) ? wv : wo;
        dst = (w == 0) ? wqh : (w == 1) ? wkh : (w == 2) ? wvh : woh;
        off = (size_t)o * 8;
    }
    float4 v0 = *(const float4*)(src + off);
    float4 v1 = *(const float4*)(src + off + 4);
    s8h y;
    y[0]=(_Float16)v0.x; y[1]=(_Float16)v0.y; y[2]=(_Float16)v0.z; y[3]=(_Float16)v0.w;
    y[4]=(_Float16)v1.x; y[5]=(_Float16)v1.y; y[6]=(_Float16)v1.z; y[7]=(_Float16)v1.w;
    *(s8h*)(dst + off) = y;
}

// ---------------- RoPE cos/sin table [SEQ][32] float2 ----------------
__global__ __launch_bounds__(256) void rope_table_kernel(float2* __restrict__ tbl) {
    int idx = blockIdx.x * 256 + threadIdx.x;     // 65536
    int s = idx >> 5, i = idx & 31;
    float freq = powf(10000.0f, -(float)(2 * i) * (1.0f / 64.0f));
    float ang  = (float)s * freq;
    tbl[idx] = make_float2(cosf(ang), sinf(ang));
}

// ---------------- f16 GEMM NT: C[rb+128][cb+128] = A*B^T, K=DIM -----------
// m97-proven structure: 128x128 tile, BK=64, 4 waves (2x2 of 64x64),
// LINEAR LDS [128][64] staged by global_load_lds (no swizzle; T2 null at 2ph).
template <bool F32OUT>
__device__ __forceinline__ void gemm_core(const _Float16* __restrict__ A,
                                          const _Float16* __restrict__ Bw,
                                          void* __restrict__ C, int ldc,
                                          int rowBase, int colBase) {
    __shared__ _Float16 As[128][64];
    __shared__ _Float16 Bs[128][64];
    const int tid = threadIdx.x, wid = tid >> 6, l = tid & 63;
    const int g = l >> 4, li = l & 15;
    const int wr = wid >> 1, wc = wid & 1;

    f32x4 acc[4][4];
#pragma unroll
    for (int m = 0; m < 4; ++m)
#pragma unroll
        for (int n = 0; n < 4; ++n) acc[m][n] = (f32x4){0.f, 0.f, 0.f, 0.f};

    const int srow = l >> 3;       // row within 8-row chunk
    const int schunk = l & 7;      // 16B chunk within row (LINEAR)

    for (int kt = 0; kt < DIM / 64; ++kt) {
#pragma unroll
        for (int i = 0; i < 4; ++i) {
            int c = wid * 4 + i;
            gll16(A  + (size_t)(rowBase + c * 8 + srow) * DIM + kt * 64 + schunk * 8, &As[c * 8][0]);
            gll16(Bw + (size_t)(colBase + c * 8 + srow) * DIM + kt * 64 + schunk * 8, &Bs[c * 8][0]);
        }
        __syncthreads();
        s8h a[4][2], b[4][2];
#pragma unroll
        for (int m = 0; m < 4; ++m) {
            int row = wr * 64 + m * 16 + li;
            a[m][0] = *(const s8h*)&As[row][g * 8];
            a[m][1] = *(const s8h*)&As[row][32 + g * 8];
        }
#pragma unroll
        for (int n = 0; n < 4; ++n) {
            int col = wc * 64 + n * 16 + li;
            b[n][0] = *(const s8h*)&Bs[col][g * 8];
            b[n][1] = *(const s8h*)&Bs[col][32 + g * 8];
        }
#pragma unroll
        for (int m = 0; m < 4; ++m)
#pragma unroll
            for (int n = 0; n < 4; ++n) {
                acc[m][n] = mfma16(a[m][0], b[n][0], acc[m][n]);
                acc[m][n] = mfma16(a[m][1], b[n][1], acc[m][n]);
            }
        __syncthreads();
    }
#pragma unroll
    for (int m = 0; m < 4; ++m)
#pragma unroll
        for (int n = 0; n < 4; ++n)
#pragma unroll
            for (int j = 0; j < 4; ++j) {
                int r = rowBase + wr * 64 + m * 16 + g * 4 + j;
                int c = colBase + wc * 64 + n * 16 + li;
                if (F32OUT) ((float*)C)[(size_t)r * ldc + c] = acc[m][n][j];
                else        ((_Float16*)C)[(size_t)r * ldc + c] = (_Float16)acc[m][n][j];
            }
}

// z=0: Q = X Wq^T   z=1: K = X Wk^T   z=2: V^T = Wv X^T (ldc = MROWS)
__global__ __launch_bounds__(256) void gemm_qkv_kernel(
    const _Float16* __restrict__ X,
    const _Float16* __restrict__ Wq, const _Float16* __restrict__ Wk,
    const _Float16* __restrict__ Wv,
    _Float16* __restrict__ Q, _Float16* __restrict__ K,
    _Float16* __restrict__ Vt) {
    if (blockIdx.z == 2) {
        // C[d][r] over 1024 x 4096: rowBase from x (8 tiles), colBase from y (32)
        gemm_core<false>(Wv, X, Vt, MROWS, blockIdx.x * 128, blockIdx.y * 128);
    } else {
        const _Float16* B = (blockIdx.z == 0) ? Wq : Wk;
        _Float16* C       = (blockIdx.z == 0) ? Q  : K;
        gemm_core<false>(X, B, C, DIM, blockIdx.y * 128, blockIdx.x * 128);
    }
}
__global__ __launch_bounds__(256) void gemm_out_kernel(
    const _Float16* __restrict__ AO, const _Float16* __restrict__ Wo,
    float* __restrict__ OUT) {
    gemm_core<true>(AO, Wo, OUT, DIM, blockIdx.y * 128, blockIdx.x * 128);
}

// ---------------- RoPE on fp16 Q,K (in place) ----------------
__global__ __launch_bounds__(256) void rope_f16_kernel(_Float16* __restrict__ Q,
                                                       _Float16* __restrict__ K,
                                                       const float2* __restrict__ tbl) {
    int id = blockIdx.x * 256 + threadIdx.x;   // [2][4096][16][4]
    int c = id & 3, h = (id >> 2) & 15, row = (id >> 6) & 4095;
    _Float16* X = (id >> 18) ? K : Q;
    int s = row & (SEQ - 1);
    size_t base = (size_t)row * DIM + h * HD + c * 8;
    s8h x1 = *(const s8h*)(X + base);
    s8h x2 = *(const s8h*)(X + base + 32);
    const float4* tp = (const float4*)(tbl + s * 32 + c * 8);
    float4 t0 = tp[0], t1 = tp[1], t2 = tp[2], t3 = tp[3];
    float cs[8] = {t0.x, t0.z, t1.x, t1.z, t2.x, t2.z, t3.x, t3.z};
    float sn[8] = {t0.y, t0.w, t1.y, t1.w, t2.y, t2.w, t3.y, t3.w};
    s8h y1, y2;
#pragma unroll
    for (int e = 0; e < 8; ++e) {
        float a = (float)x1[e], bq = (float)x2[e];
        y1[e] = (_Float16)fmaf(a, cs[e], -bq * sn[e]);
        y2[e] = (_Float16)fmaf(bq, cs[e],  a * sn[e]);
    }
    *(s8h*)(X + base)      = y1;
    *(s8h*)(X + base + 32) = y2;
}

// ---------------- flash attention: LDS-free, barrier-free, fp16 MFMA ------
// 256 thr = 4 waves, each wave INDEPENDENT, owning 16 q-rows. Grid doubled
// vs r5 (64 q-rows/block, 1024 blocks -> 16 waves/CU): occupancy was the
// bottleneck (r5: grid-capped at 8 waves/CU, MfmaUtil 7.5%, VALUBusy 16%).
// S^T = mfma(A=K, B=Q): lane (g,li) holds S^T[mt*16+g*4+jj][q=li]
//   -> softmax = in-lane chain + 2 shuffles (lanes li,li+16,li+32,li+48).
// PV: O^T = mfma(A=V^T, B=P^T). Shared k-order kappa(g,kc,e) =
//   kc*32 + (e>>2)*16 + g*4 + (e&3); slot-wise consistency cancels HW k-map.
__global__ __launch_bounds__(256, 4) void attn_kernel(const _Float16* __restrict__ Q,
                                                      const _Float16* __restrict__ K,
                                                      const _Float16* __restrict__ Vt,
                                                      _Float16* __restrict__ AO) {
    const int tid = threadIdx.x, wid = tid >> 6, l = tid & 63;
    const int g = l >> 4, li = l & 15;
    const int qt = blockIdx.x, h = blockIdx.y, b = blockIdx.z;

    const _Float16* Qh  = Q  + ((size_t)(b * SEQ) + qt * 64 + wid * 16) * DIM + h * HD;
    const _Float16* Kh  = K  + (size_t)(b * SEQ) * DIM + h * HD;
    const _Float16* Vth = Vt + (size_t)(h * HD) * MROWS + b * SEQ;
    _Float16* AOh = AO + ((size_t)(b * SEQ) + qt * 64 + wid * 16) * DIM + h * HD;

    // Q fragments: Q[q=li][d=dc*32+g*8+e]
    s8h qf[2];
#pragma unroll
    for (int dc = 0; dc < 2; ++dc)
        qf[dc] = *(const s8h*)(Qh + (size_t)li * DIM + dc * 32 + g * 8);

    f32x4 o[4];                    // O^T[d=mtd*16+g*4+jj][q=li]
    float mrun = -INFINITY, lrun = 0.f;
#pragma unroll
    for (int mtd = 0; mtd < 4; ++mtd) o[mtd] = (f32x4){0.f, 0.f, 0.f, 0.f};

    const float C1 = 0.125f * 1.44269504088896f;   // 1/sqrt(64) * log2(e)

    for (int kt = 0; kt < NT; ++kt) {
        // ---- S^T = K * Q^T (K frags straight from global/L2) ----
        f32x4 st[4];
#pragma unroll
        for (int mt = 0; mt < 4; ++mt) st[mt] = (f32x4){0.f, 0.f, 0.f, 0.f};
#pragma unroll
        for (int mt = 0; mt < 4; ++mt) {
            const _Float16* kp = Kh + (size_t)(kt * 64 + mt * 16 + li) * DIM + g * 8;
            s8h k0 = *(const s8h*)(kp);
            s8h k1 = *(const s8h*)(kp + 32);
            st[mt] = mfma16(k0, qf[0], st[mt]);
            st[mt] = mfma16(k1, qf[1], st[mt]);
        }

        // ---- V^T fragments: issue early so latency hides under softmax ----
        s4h va[4][2][2];
#pragma unroll
        for (int mtd = 0; mtd < 4; ++mtd)
#pragma unroll
            for (int kc = 0; kc < 2; ++kc) {
                const _Float16* vp =
                    Vth + (size_t)(mtd * 16 + li) * MROWS + kt * 64 + kc * 32 + g * 4;
                va[mtd][kc][0] = *(const s4h*)(vp);
                va[mtd][kc][1] = *(const s4h*)(vp + 16);
            }

        // ---- online softmax for q-col li; kpos spread over mt,g,jj ----
        {
            float tm = st[0][0];
#pragma unroll
            for (int mt = 0; mt < 4; ++mt)
#pragma unroll
                for (int jj = 0; jj < 4; ++jj)
                    if (mt || jj) tm = fmaxf(tm, st[mt][jj]);
            tm = fmaxf(tm, __shfl_xor(tm, 16));
            tm = fmaxf(tm, __shfl_xor(tm, 32));
            float mo = mrun;
            float mn = fmaxf(mo, tm);
            float alpha = ex2((mo - mn) * C1);
            float rs = 0.f;
#pragma unroll
            for (int mt = 0; mt < 4; ++mt)
#pragma unroll
                for (int jj = 0; jj < 4; ++jj) {
                    float p = ex2((st[mt][jj] - mn) * C1);
                    st[mt][jj] = p;
                    rs += p;
                }
            rs += __shfl_xor(rs, 16);
            rs += __shfl_xor(rs, 32);
            lrun = lrun * alpha + rs;
            mrun = mn;
#pragma unroll
            for (int mtd = 0; mtd < 4; ++mtd) {
                o[mtd][0] *= alpha; o[mtd][1] *= alpha;
                o[mtd][2] *= alpha; o[mtd][3] *= alpha;
            }
        }

        // ---- P^T -> f16 B-fragments in k-order kappa ----
        s8h pb[2];
#pragma unroll
        for (int kc = 0; kc < 2; ++kc)
#pragma unroll
            for (int e = 0; e < 8; ++e)
                pb[kc][e] = (_Float16)st[kc * 2 + (e >> 2)][e & 3];

        // ---- O^T += V^T * P^T ----
#pragma unroll
        for (int mtd = 0; mtd < 4; ++mtd)
#pragma unroll
            for (int kc = 0; kc < 2; ++kc) {
                s8h v8;
#pragma unroll
                for (int e = 0; e < 4; ++e) { v8[e] = va[mtd][kc][0][e]; v8[4 + e] = va[mtd][kc][1][e]; }
                o[mtd] = mfma16(v8, pb[kc], o[mtd]);
            }
    }

    // ---- epilogue: normalize, 8B packed stores ----
    {
        float inv = 1.0f / lrun;
#pragma unroll
        for (int mtd = 0; mtd < 4; ++mtd) {
            s4h w;
#pragma unroll
            for (int jj = 0; jj < 4; ++jj) w[jj] = (_Float16)(o[mtd][jj] * inv);
            *(s4h*)(AOh + (size_t)li * DIM + mtd * 16 + g * 4) = w;
        }
    }
}

// ---------------- launch ----------------
extern "C" void kernel_launch(void* const* d_in, const int* in_sizes, int n_in,
                              void* d_out, int out_size, void* d_ws, size_t ws_size,
                              hipStream_t stream) {
    const float* x  = (const float*)d_in[0];
    const float* Wq = (const float*)d_in[1];
    const float* Wk = (const float*)d_in[2];
    const float* Wv = (const float*)d_in[3];
    const float* Wo = (const float*)d_in[4];
    float* out = (float*)d_out;

    char* ws = (char*)d_ws;
    _Float16* xh  = (_Float16*)(ws);
    _Float16* Wqh = (_Float16*)(ws + 8388608);
    _Float16* Wkh = (_Float16*)(ws + 10485760);
    _Float16* Wvh = (_Float16*)(ws + 12582912);
    _Float16* Woh = (_Float16*)(ws + 14680064);
    _Float16* Qh  = (_Float16*)(ws + 16777216);
    _Float16* Kh  = (_Float16*)(ws + 25165824);
    _Float16* Vth = (_Float16*)(ws + 33554432);   // V^T [1024][4096]
    _Float16* AOh = (_Float16*)(ws + 41943040);
    float2*   tbl = (float2*)  (ws + 50331648);

    cast_f16_kernel<<<4096, 256, 0, stream>>>(x, Wq, Wk, Wv, Wo, xh, Wqh, Wkh, Wvh, Woh);
    rope_table_kernel<<<256, 256, 0, stream>>>(tbl);
    gemm_qkv_kernel<<<dim3(8, 32, 3), 256, 0, stream>>>(xh, Wqh, Wkh, Wvh, Qh, Kh, Vth);
    rope_f16_kernel<<<2048, 256, 0, stream>>>(Qh, Kh, tbl);
    attn_kernel<<<dim3(32, 16, 2), 256, 0, stream>>>(Qh, Kh, Vth, AOh);
    gemm_out_kernel<<<dim3(8, 32), 256, 0, stream>>>(AOh, Woh, out);
}

// Round 7
// 327.011 us; speedup vs baseline: 1.5448x; 1.5448x over previous
//
#include <hip/hip_runtime.h>

#define DIM   1024
#define NHEAD 16
#define HD    64
#define SEQ   2048
#define BATCH 2
#define MROWS (BATCH * SEQ)   // 4096
#define NT    (SEQ / 64)      // 32 KV tiles

typedef __attribute__((ext_vector_type(8))) _Float16 s8h;   // 8 f16 in 4 VGPRs
typedef __attribute__((ext_vector_type(4))) _Float16 s4h;   // 4 f16 (8B)
typedef __attribute__((ext_vector_type(4))) float f32x4;

typedef const __attribute__((address_space(1))) unsigned GU;
typedef __attribute__((address_space(3))) unsigned LU;

__device__ __forceinline__ void gll16(const void* g, void* l) {
    // async global->LDS, 16B/lane; LDS dest = wave-uniform base + lane*16
    __builtin_amdgcn_global_load_lds((GU*)g, (LU*)l, 16, 0, 0);
}
__device__ __forceinline__ f32x4 mfma16(s8h a, s8h b, f32x4 c) {
    return __builtin_amdgcn_mfma_f32_16x16x32_f16(a, b, c, 0, 0, 0);
}
// 2^x via v_exp_f32. NOTE: not named __exp2f (glibc owns that symbol).
__device__ __forceinline__ float ex2(float x) {
    return __builtin_amdgcn_exp2f(x);
}

// ---------------- fp32 -> fp16 cast: x | Wq | Wk | Wv | Wo ----------------
__global__ __launch_bounds__(256) void cast_f16_kernel(
    const float* __restrict__ x,  const float* __restrict__ wq,
    const float* __restrict__ wk, const float* __restrict__ wv,
    const float* __restrict__ wo,
    _Float16* __restrict__ xh,  _Float16* __restrict__ wqh,
    _Float16* __restrict__ wkh, _Float16* __restrict__ wvh,
    _Float16* __restrict__ woh) {
    int id = blockIdx.x * 256 + threadIdx.x;   // 1,048,576 threads x 8 elems
    const float* src; _Float16* dst; size_t off;
    if (id < 524288) { src = x; dst = xh; off = (size_t)id * 8; }
    else {
        int r = id - 524288, w = r >> 17, o = r & 131071;
        src = (w == 0) ? wq : (w == 1) ? wk : (w == 2) ? wv : wo;
        dst = (w == 0) ? wqh : (w == 1) ? wkh : (w == 2) ? wvh : woh;
        off = (size_t)o * 8;
    }
    float4 v0 = *(const float4*)(src + off);
    float4 v1 = *(const float4*)(src + off + 4);
    s8h y;
    y[0]=(_Float16)v0.x; y[1]=(_Float16)v0.y; y[2]=(_Float16)v0.z; y[3]=(_Float16)v0.w;
    y[4]=(_Float16)v1.x; y[5]=(_Float16)v1.y; y[6]=(_Float16)v1.z; y[7]=(_Float16)v1.w;
    *(s8h*)(dst + off) = y;
}

// ---------------- RoPE cos/sin table [SEQ][32] float2 ----------------
__global__ __launch_bounds__(256) void rope_table_kernel(float2* __restrict__ tbl) {
    int idx = blockIdx.x * 256 + threadIdx.x;     // 65536
    int s = idx >> 5, i = idx & 31;
    float freq = powf(10000.0f, -(float)(2 * i) * (1.0f / 64.0f));
    float ang  = (float)s * freq;
    tbl[idx] = make_float2(cosf(ang), sinf(ang));
}

// ---------------- f16 GEMM NT: C[rb+128][cb+128] = A*B^T, K=DIM -----------
// m97-proven structure: 128x128 tile, BK=64, 4 waves (2x2 of 64x64),
// LINEAR LDS [128][64] staged by global_load_lds (no swizzle; T2 null at 2ph).
template <bool F32OUT>
__device__ __forceinline__ void gemm_core(const _Float16* __restrict__ A,
                                          const _Float16* __restrict__ Bw,
                                          void* __restrict__ C, int ldc,
                                          int rowBase, int colBase) {
    __shared__ _Float16 As[128][64];
    __shared__ _Float16 Bs[128][64];
    const int tid = threadIdx.x, wid = tid >> 6, l = tid & 63;
    const int g = l >> 4, li = l & 15;
    const int wr = wid >> 1, wc = wid & 1;

    f32x4 acc[4][4];
#pragma unroll
    for (int m = 0; m < 4; ++m)
#pragma unroll
        for (int n = 0; n < 4; ++n) acc[m][n] = (f32x4){0.f, 0.f, 0.f, 0.f};

    const int srow = l >> 3;       // row within 8-row chunk
    const int schunk = l & 7;      // 16B chunk within row (LINEAR)

    for (int kt = 0; kt < DIM / 64; ++kt) {
#pragma unroll
        for (int i = 0; i < 4; ++i) {
            int c = wid * 4 + i;
            gll16(A  + (size_t)(rowBase + c * 8 + srow) * DIM + kt * 64 + schunk * 8, &As[c * 8][0]);
            gll16(Bw + (size_t)(colBase + c * 8 + srow) * DIM + kt * 64 + schunk * 8, &Bs[c * 8][0]);
        }
        __syncthreads();
        s8h a[4][2], b[4][2];
#pragma unroll
        for (int m = 0; m < 4; ++m) {
            int row = wr * 64 + m * 16 + li;
            a[m][0] = *(const s8h*)&As[row][g * 8];
            a[m][1] = *(const s8h*)&As[row][32 + g * 8];
        }
#pragma unroll
        for (int n = 0; n < 4; ++n) {
            int col = wc * 64 + n * 16 + li;
            b[n][0] = *(const s8h*)&Bs[col][g * 8];
            b[n][1] = *(const s8h*)&Bs[col][32 + g * 8];
        }
#pragma unroll
        for (int m = 0; m < 4; ++m)
#pragma unroll
            for (int n = 0; n < 4; ++n) {
                acc[m][n] = mfma16(a[m][0], b[n][0], acc[m][n]);
                acc[m][n] = mfma16(a[m][1], b[n][1], acc[m][n]);
            }
        __syncthreads();
    }
#pragma unroll
    for (int m = 0; m < 4; ++m)
#pragma unroll
        for (int n = 0; n < 4; ++n)
#pragma unroll
            for (int j = 0; j < 4; ++j) {
                int r = rowBase + wr * 64 + m * 16 + g * 4 + j;
                int c = colBase + wc * 64 + n * 16 + li;
                if (F32OUT) ((float*)C)[(size_t)r * ldc + c] = acc[m][n][j];
                else        ((_Float16*)C)[(size_t)r * ldc + c] = (_Float16)acc[m][n][j];
            }
}

// z=0: Q = X Wq^T   z=1: K = X Wk^T   z=2: V^T = Wv X^T (ldc = MROWS)
__global__ __launch_bounds__(256) void gemm_qkv_kernel(
    const _Float16* __restrict__ X,
    const _Float16* __restrict__ Wq, const _Float16* __restrict__ Wk,
    const _Float16* __restrict__ Wv,
    _Float16* __restrict__ Q, _Float16* __restrict__ K,
    _Float16* __restrict__ Vt) {
    if (blockIdx.z == 2) {
        // C[d][r] over 1024 x 4096: rowBase from x (8 tiles), colBase from y (32)
        gemm_core<false>(Wv, X, Vt, MROWS, blockIdx.x * 128, blockIdx.y * 128);
    } else {
        const _Float16* B = (blockIdx.z == 0) ? Wq : Wk;
        _Float16* C       = (blockIdx.z == 0) ? Q  : K;
        gemm_core<false>(X, B, C, DIM, blockIdx.y * 128, blockIdx.x * 128);
    }
}
__global__ __launch_bounds__(256) void gemm_out_kernel(
    const _Float16* __restrict__ AO, const _Float16* __restrict__ Wo,
    float* __restrict__ OUT) {
    gemm_core<true>(AO, Wo, OUT, DIM, blockIdx.y * 128, blockIdx.x * 128);
}

// ---------------- RoPE on fp16 Q,K (in place) ----------------
__global__ __launch_bounds__(256) void rope_f16_kernel(_Float16* __restrict__ Q,
                                                       _Float16* __restrict__ K,
                                                       const float2* __restrict__ tbl) {
    int id = blockIdx.x * 256 + threadIdx.x;   // [2][4096][16][4]
    int c = id & 3, h = (id >> 2) & 15, row = (id >> 6) & 4095;
    _Float16* X = (id >> 18) ? K : Q;
    int s = row & (SEQ - 1);
    size_t base = (size_t)row * DIM + h * HD + c * 8;
    s8h x1 = *(const s8h*)(X + base);
    s8h x2 = *(const s8h*)(X + base + 32);
    const float4* tp = (const float4*)(tbl + s * 32 + c * 8);
    float4 t0 = tp[0], t1 = tp[1], t2 = tp[2], t3 = tp[3];
    float cs[8] = {t0.x, t0.z, t1.x, t1.z, t2.x, t2.z, t3.x, t3.z};
    float sn[8] = {t0.y, t0.w, t1.y, t1.w, t2.y, t2.w, t3.y, t3.w};
    s8h y1, y2;
#pragma unroll
    for (int e = 0; e < 8; ++e) {
        float a = (float)x1[e], bq = (float)x2[e];
        y1[e] = (_Float16)fmaf(a, cs[e], -bq * sn[e]);
        y2[e] = (_Float16)fmaf(bq, cs[e],  a * sn[e]);
    }
    *(s8h*)(X + base)      = y1;
    *(s8h*)(X + base + 32) = y2;
}

// ---------------- flash attention: LDS-shared K/V, fp16 MFMA ----------------
// r6 lesson: per-wave K/V^T global reads hit a ~6 TB/s L1/L2 ceiling (r5 1.07GB
// /182us, r6 2.1GB/348us — both 5.9 TB/s). Fix: stage K (64x64) and V^T (64x64)
// tiles in LDS ONCE PER BLOCK (4 waves share) -> 4x traffic cut. Staging is the
// proven GEMM gll16 linear pattern; frag reads fetch the same bytes as r5.
// One barrier/tile, double-buffered; stage(kt+1) flies under compute(kt).
// S^T = mfma(A=K, B=Q); softmax in-register + 2 shuffles; PV with shared
// k-order kappa(g,kc,e) = kc*32 + (e>>2)*16 + g*4 + (e&3).
__global__ __launch_bounds__(256, 2) void attn_kernel(const _Float16* __restrict__ Q,
                                                      const _Float16* __restrict__ K,
                                                      const _Float16* __restrict__ Vt,
                                                      _Float16* __restrict__ AO) {
    __shared__ _Float16 Ks[2][64][64];   // [buf][kpos][d]
    __shared__ _Float16 Vs[2][64][64];   // [buf][d][kpos]

    const int tid = threadIdx.x, wid = tid >> 6, l = tid & 63;
    const int g = l >> 4, li = l & 15;
    const int qt = blockIdx.x, h = blockIdx.y, b = blockIdx.z;

    const _Float16* Qh  = Q  + ((size_t)(b * SEQ) + qt * 128 + wid * 32) * DIM + h * HD;
    const _Float16* Kh  = K  + (size_t)(b * SEQ) * DIM + h * HD;
    const _Float16* Vth = Vt + (size_t)(h * HD) * MROWS + b * SEQ;
    _Float16* AOh = AO + ((size_t)(b * SEQ) + qt * 128 + wid * 32) * DIM + h * HD;

    const int srow = l >> 3;       // staging: row within 8-row chunk
    const int schunk = l & 7;      // staging: 16B chunk within row (linear)

    // Q fragments: Q[q=nt*16+li][d=dc*32+g*8+e]
    s8h qf[2][2];
#pragma unroll
    for (int nt = 0; nt < 2; ++nt)
#pragma unroll
        for (int dc = 0; dc < 2; ++dc)
            qf[nt][dc] = *(const s8h*)(Qh + (size_t)(nt * 16 + li) * DIM + dc * 32 + g * 8);

    f32x4 o[4][2];                 // O^T[d=mtd*16+g*4+jj][q=nt*16+li]
    float mrun[2], lrun[2];
#pragma unroll
    for (int nt = 0; nt < 2; ++nt) { mrun[nt] = -INFINITY; lrun[nt] = 0.f; }
#pragma unroll
    for (int mtd = 0; mtd < 4; ++mtd)
#pragma unroll
        for (int nt = 0; nt < 2; ++nt) o[mtd][nt] = (f32x4){0.f, 0.f, 0.f, 0.f};

    const float C1 = 0.125f * 1.44269504088896f;   // 1/sqrt(64) * log2(e)

    // prologue: stage tile 0 into buf 0 (wave wid stages rows wid*16..+15)
#pragma unroll
    for (int i = 0; i < 2; ++i) {
        int r = wid * 16 + i * 8;
        gll16(Kh  + (size_t)(r + srow) * DIM   + schunk * 8, &Ks[0][r][0]);
        gll16(Vth + (size_t)(r + srow) * MROWS + schunk * 8, &Vs[0][r][0]);
    }

    for (int kt = 0; kt < NT; ++kt) {
        const int buf = kt & 1;
        __syncthreads();   // drains staging vmcnt; buf ready, buf^1 free

        // stage next tile early: loads fly under QK^T + softmax + PV
        if (kt + 1 < NT) {
#pragma unroll
            for (int i = 0; i < 2; ++i) {
                int r = wid * 16 + i * 8;
                gll16(Kh  + (size_t)((kt + 1) * 64 + r + srow) * DIM + schunk * 8,
                      &Ks[buf ^ 1][r][0]);
                gll16(Vth + (size_t)(r + srow) * MROWS + (kt + 1) * 64 + schunk * 8,
                      &Vs[buf ^ 1][r][0]);
            }
        }

        // ---- S^T = K * Q^T (K frags from LDS) ----
        f32x4 st[4][2];
#pragma unroll
        for (int mt = 0; mt < 4; ++mt)
#pragma unroll
            for (int nt = 0; nt < 2; ++nt) st[mt][nt] = (f32x4){0.f, 0.f, 0.f, 0.f};
#pragma unroll
        for (int mt = 0; mt < 4; ++mt) {
            s8h k0 = *(const s8h*)&Ks[buf][mt * 16 + li][g * 8];
            s8h k1 = *(const s8h*)&Ks[buf][mt * 16 + li][32 + g * 8];
#pragma unroll
            for (int nt = 0; nt < 2; ++nt) {
                st[mt][nt] = mfma16(k0, qf[nt][0], st[mt][nt]);
                st[mt][nt] = mfma16(k1, qf[nt][1], st[mt][nt]);
            }
        }

        // ---- V^T fragments from LDS ----
        s4h va[4][2][2];
#pragma unroll
        for (int mtd = 0; mtd < 4; ++mtd)
#pragma unroll
            for (int kc = 0; kc < 2; ++kc) {
                va[mtd][kc][0] = *(const s4h*)&Vs[buf][mtd * 16 + li][kc * 32 + g * 4];
                va[mtd][kc][1] = *(const s4h*)&Vs[buf][mtd * 16 + li][kc * 32 + g * 4 + 16];
            }

        // ---- online softmax per q (=nt,li); kpos spread over mt,g,jj ----
#pragma unroll
        for (int nt = 0; nt < 2; ++nt) {
            float tm = st[0][nt][0];
#pragma unroll
            for (int mt = 0; mt < 4; ++mt)
#pragma unroll
                for (int jj = 0; jj < 4; ++jj)
                    if (mt || jj) tm = fmaxf(tm, st[mt][nt][jj]);
            tm = fmaxf(tm, __shfl_xor(tm, 16));
            tm = fmaxf(tm, __shfl_xor(tm, 32));
            float mo = mrun[nt];
            float mn = fmaxf(mo, tm);
            float alpha = ex2((mo - mn) * C1);
            float rs = 0.f;
#pragma unroll
            for (int mt = 0; mt < 4; ++mt)
#pragma unroll
                for (int jj = 0; jj < 4; ++jj) {
                    float p = ex2((st[mt][nt][jj] - mn) * C1);
                    st[mt][nt][jj] = p;
                    rs += p;
                }
            rs += __shfl_xor(rs, 16);
            rs += __shfl_xor(rs, 32);
            lrun[nt] = lrun[nt] * alpha + rs;
            mrun[nt] = mn;
#pragma unroll
            for (int mtd = 0; mtd < 4; ++mtd) {
                o[mtd][nt][0] *= alpha; o[mtd][nt][1] *= alpha;
                o[mtd][nt][2] *= alpha; o[mtd][nt][3] *= alpha;
            }
        }

        // ---- P^T -> f16 B-fragments in k-order kappa ----
        s8h pb[2][2];
#pragma unroll
        for (int nt = 0; nt < 2; ++nt)
#pragma unroll
            for (int kc = 0; kc < 2; ++kc)
#pragma unroll
                for (int e = 0; e < 8; ++e)
                    pb[nt][kc][e] = (_Float16)st[kc * 2 + (e >> 2)][nt][e & 3];

        // ---- O^T += V^T * P^T ----
#pragma unroll
        for (int mtd = 0; mtd < 4; ++mtd)
#pragma unroll
            for (int kc = 0; kc < 2; ++kc) {
                s8h v8;
#pragma unroll
                for (int e = 0; e < 4; ++e) { v8[e] = va[mtd][kc][0][e]; v8[4 + e] = va[mtd][kc][1][e]; }
#pragma unroll
                for (int nt = 0; nt < 2; ++nt)
                    o[mtd][nt] = mfma16(v8, pb[nt][kc], o[mtd][nt]);
            }
    }

    // ---- epilogue: normalize, 8B packed stores ----
#pragma unroll
    for (int nt = 0; nt < 2; ++nt) {
        float inv = 1.0f / lrun[nt];
#pragma unroll
        for (int mtd = 0; mtd < 4; ++mtd) {
            s4h w;
#pragma unroll
            for (int jj = 0; jj < 4; ++jj) w[jj] = (_Float16)(o[mtd][nt][jj] * inv);
            *(s4h*)(AOh + (size_t)(nt * 16 + li) * DIM + mtd * 16 + g * 4) = w;
        }
    }
}

// ---------------- launch ----------------
extern "C" void kernel_launch(void* const* d_in, const int* in_sizes, int n_in,
                              void* d_out, int out_size, void* d_ws, size_t ws_size,
                              hipStream_t stream) {
    const float* x  = (const float*)d_in[0];
    const float* Wq = (const float*)d_in[1];
    const float* Wk = (const float*)d_in[2];
    const float* Wv = (const float*)d_in[3];
    const float* Wo = (const float*)d_in[4];
    float* out = (float*)d_out;

    char* ws = (char*)d_ws;
    _Float16* xh  = (_Float16*)(ws);
    _Float16* Wqh = (_Float16*)(ws + 8388608);
    _Float16* Wkh = (_Float16*)(ws + 10485760);
    _Float16* Wvh = (_Float16*)(ws + 12582912);
    _Float16* Woh = (_Float16*)(ws + 14680064);
    _Float16* Qh  = (_Float16*)(ws + 16777216);
    _Float16* Kh  = (_Float16*)(ws + 25165824);
    _Float16* Vth = (_Float16*)(ws + 33554432);   // V^T [1024][4096]
    _Float16* AOh = (_Float16*)(ws + 41943040);
    float2*   tbl = (float2*)  (ws + 50331648);

    cast_f16_kernel<<<4096, 256, 0, stream>>>(x, Wq, Wk, Wv, Wo, xh, Wqh, Wkh, Wvh, Woh);
    rope_table_kernel<<<256, 256, 0, stream>>>(tbl);
    gemm_qkv_kernel<<<dim3(8, 32, 3), 256, 0, stream>>>(xh, Wqh, Wkh, Wvh, Qh, Kh, Vth);
    rope_f16_kernel<<<2048, 256, 0, stream>>>(Qh, Kh, tbl);
    attn_kernel<<<dim3(16, 16, 2), 256, 0, stream>>>(Qh, Kh, Vth, AOh);
    gemm_out_kernel<<<dim3(8, 32), 256, 0, stream>>>(AOh, Woh, out);
}

// Round 8
// 233.698 us; speedup vs baseline: 2.1616x; 1.3993x over previous
//
#include <hip/hip_runtime.h>

#define DIM   1024
#define NHEAD 16
#define HD    64
#define SEQ   2048
#define BATCH 2
#define MROWS (BATCH * SEQ)   // 4096
#define NT    (SEQ / 64)      // 32 KV tiles

typedef __attribute__((ext_vector_type(8))) _Float16 s8h;   // 8 f16 in 4 VGPRs
typedef __attribute__((ext_vector_type(4))) _Float16 s4h;   // 4 f16 (8B)
typedef __attribute__((ext_vector_type(4))) float f32x4;

typedef const __attribute__((address_space(1))) unsigned GU;
typedef __attribute__((address_space(3))) unsigned LU;

__device__ __forceinline__ void gll16(const void* g, void* l) {
    // async global->LDS, 16B/lane; LDS dest = wave-uniform base + lane*16
    __builtin_amdgcn_global_load_lds((GU*)g, (LU*)l, 16, 0, 0);
}
__device__ __forceinline__ f32x4 mfma16(s8h a, s8h b, f32x4 c) {
    return __builtin_amdgcn_mfma_f32_16x16x32_f16(a, b, c, 0, 0, 0);
}
// 2^x via v_exp_f32. NOTE: not named __exp2f (glibc owns that symbol).
__device__ __forceinline__ float ex2(float x) {
    return __builtin_amdgcn_exp2f(x);
}

// ---------------- fp32 -> fp16 cast: x | Wq | Wk | Wv | Wo ----------------
__global__ __launch_bounds__(256) void cast_f16_kernel(
    const float* __restrict__ x,  const float* __restrict__ wq,
    const float* __restrict__ wk, const float* __restrict__ wv,
    const float* __restrict__ wo,
    _Float16* __restrict__ xh,  _Float16* __restrict__ wqh,
    _Float16* __restrict__ wkh, _Float16* __restrict__ wvh,
    _Float16* __restrict__ woh) {
    int id = blockIdx.x * 256 + threadIdx.x;   // 1,048,576 threads x 8 elems
    const float* src; _Float16* dst; size_t off;
    if (id < 524288) { src = x; dst = xh; off = (size_t)id * 8; }
    else {
        int r = id - 524288, w = r >> 17, o = r & 131071;
        src = (w == 0) ? wq : (w == 1) ? wk : (w == 2) ? wv : wo;
        dst = (w == 0) ? wqh : (w == 1) ? wkh : (w == 2) ? wvh : woh;
        off = (size_t)o * 8;
    }
    float4 v0 = *(const float4*)(src + off);
    float4 v1 = *(const float4*)(src + off + 4);
    s8h y;
    y[0]=(_Float16)v0.x; y[1]=(_Float16)v0.y; y[2]=(_Float16)v0.z; y[3]=(_Float16)v0.w;
    y[4]=(_Float16)v1.x; y[5]=(_Float16)v1.y; y[6]=(_Float16)v1.z; y[7]=(_Float16)v1.w;
    *(s8h*)(dst + off) = y;
}

// ---------------- RoPE cos/sin table [SEQ][32] float2 ----------------
__global__ __launch_bounds__(256) void rope_table_kernel(float2* __restrict__ tbl) {
    int idx = blockIdx.x * 256 + threadIdx.x;     // 65536
    int s = idx >> 5, i = idx & 31;
    float freq = powf(10000.0f, -(float)(2 * i) * (1.0f / 64.0f));
    float ang  = (float)s * freq;
    tbl[idx] = make_float2(cosf(ang), sinf(ang));
}

// ---------------- f16 GEMM NT: C[rb+128][cb+128] = A*B^T, K=DIM -----------
// m97-proven structure: 128x128 tile, BK=64, 4 waves (2x2 of 64x64),
// LINEAR LDS [128][64] staged by global_load_lds (no swizzle; T2 null at 2ph).
template <bool F32OUT>
__device__ __forceinline__ void gemm_core(const _Float16* __restrict__ A,
                                          const _Float16* __restrict__ Bw,
                                          void* __restrict__ C, int ldc,
                                          int rowBase, int colBase) {
    __shared__ _Float16 As[128][64];
    __shared__ _Float16 Bs[128][64];
    const int tid = threadIdx.x, wid = tid >> 6, l = tid & 63;
    const int g = l >> 4, li = l & 15;
    const int wr = wid >> 1, wc = wid & 1;

    f32x4 acc[4][4];
#pragma unroll
    for (int m = 0; m < 4; ++m)
#pragma unroll
        for (int n = 0; n < 4; ++n) acc[m][n] = (f32x4){0.f, 0.f, 0.f, 0.f};

    const int srow = l >> 3;       // row within 8-row chunk
    const int schunk = l & 7;      // 16B chunk within row (LINEAR)

    for (int kt = 0; kt < DIM / 64; ++kt) {
#pragma unroll
        for (int i = 0; i < 4; ++i) {
            int c = wid * 4 + i;
            gll16(A  + (size_t)(rowBase + c * 8 + srow) * DIM + kt * 64 + schunk * 8, &As[c * 8][0]);
            gll16(Bw + (size_t)(colBase + c * 8 + srow) * DIM + kt * 64 + schunk * 8, &Bs[c * 8][0]);
        }
        __syncthreads();
        s8h a[4][2], b[4][2];
#pragma unroll
        for (int m = 0; m < 4; ++m) {
            int row = wr * 64 + m * 16 + li;
            a[m][0] = *(const s8h*)&As[row][g * 8];
            a[m][1] = *(const s8h*)&As[row][32 + g * 8];
        }
#pragma unroll
        for (int n = 0; n < 4; ++n) {
            int col = wc * 64 + n * 16 + li;
            b[n][0] = *(const s8h*)&Bs[col][g * 8];
            b[n][1] = *(const s8h*)&Bs[col][32 + g * 8];
        }
#pragma unroll
        for (int m = 0; m < 4; ++m)
#pragma unroll
            for (int n = 0; n < 4; ++n) {
                acc[m][n] = mfma16(a[m][0], b[n][0], acc[m][n]);
                acc[m][n] = mfma16(a[m][1], b[n][1], acc[m][n]);
            }
        __syncthreads();
    }
#pragma unroll
    for (int m = 0; m < 4; ++m)
#pragma unroll
        for (int n = 0; n < 4; ++n)
#pragma unroll
            for (int j = 0; j < 4; ++j) {
                int r = rowBase + wr * 64 + m * 16 + g * 4 + j;
                int c = colBase + wc * 64 + n * 16 + li;
                if (F32OUT) ((float*)C)[(size_t)r * ldc + c] = acc[m][n][j];
                else        ((_Float16*)C)[(size_t)r * ldc + c] = (_Float16)acc[m][n][j];
            }
}

// z=0: Q = X Wq^T   z=1: K = X Wk^T   z=2: V^T = Wv X^T (ldc = MROWS)
__global__ __launch_bounds__(256) void gemm_qkv_kernel(
    const _Float16* __restrict__ X,
    const _Float16* __restrict__ Wq, const _Float16* __restrict__ Wk,
    const _Float16* __restrict__ Wv,
    _Float16* __restrict__ Q, _Float16* __restrict__ K,
    _Float16* __restrict__ Vt) {
    if (blockIdx.z == 2) {
        // C[d][r] over 1024 x 4096: rowBase from x (8 tiles), colBase from y (32)
        gemm_core<false>(Wv, X, Vt, MROWS, blockIdx.x * 128, blockIdx.y * 128);
    } else {
        const _Float16* B = (blockIdx.z == 0) ? Wq : Wk;
        _Float16* C       = (blockIdx.z == 0) ? Q  : K;
        gemm_core<false>(X, B, C, DIM, blockIdx.y * 128, blockIdx.x * 128);
    }
}
__global__ __launch_bounds__(256) void gemm_out_kernel(
    const _Float16* __restrict__ AO, const _Float16* __restrict__ Wo,
    float* __restrict__ OUT) {
    gemm_core<true>(AO, Wo, OUT, DIM, blockIdx.y * 128, blockIdx.x * 128);
}

// ---------------- RoPE on fp16 Q,K (in place) ----------------
__global__ __launch_bounds__(256) void rope_f16_kernel(_Float16* __restrict__ Q,
                                                       _Float16* __restrict__ K,
                                                       const float2* __restrict__ tbl) {
    int id = blockIdx.x * 256 + threadIdx.x;   // [2][4096][16][4]
    int c = id & 3, h = (id >> 2) & 15, row = (id >> 6) & 4095;
    _Float16* X = (id >> 18) ? K : Q;
    int s = row & (SEQ - 1);
    size_t base = (size_t)row * DIM + h * HD + c * 8;
    s8h x1 = *(const s8h*)(X + base);
    s8h x2 = *(const s8h*)(X + base + 32);
    const float4* tp = (const float4*)(tbl + s * 32 + c * 8);
    float4 t0 = tp[0], t1 = tp[1], t2 = tp[2], t3 = tp[3];
    float cs[8] = {t0.x, t0.z, t1.x, t1.z, t2.x, t2.z, t3.x, t3.z};
    float sn[8] = {t0.y, t0.w, t1.y, t1.w, t2.y, t2.w, t3.y, t3.w};
    s8h y1, y2;
#pragma unroll
    for (int e = 0; e < 8; ++e) {
        float a = (float)x1[e], bq = (float)x2[e];
        y1[e] = (_Float16)fmaf(a, cs[e], -bq * sn[e]);
        y2[e] = (_Float16)fmaf(bq, cs[e],  a * sn[e]);
    }
    *(s8h*)(X + base)      = y1;
    *(s8h*)(X + base + 32) = y2;
}

// ---------------- flash attention: LDS-shared K/V + XOR swizzle ------------
// r7 lesson: LDS staging cut the 6 TB/s global-path wall, but linear [64][64]
// tiles gave 16-way bank conflicts (6.9e7 cycles ~ 68% of kernel): all 16
// lanes of a quarter-wave read one 16B chunk-column (128B row stride).
// Fix (T2, rule #21): keep gll16 LINEAR dest, pre-swizzle the GLOBAL source
// chunk (l&7)^(l>>3), and XOR the read chunk with row&7:
//   LDS[row][c] = src[row][c ^ (row&7)]  (involution, bijective per 8 rows)
// After swizzle each quarter-wave spreads over 8 chunks -> 2 lanes/chunk.
// S^T = mfma(A=K, B=Q); softmax in-register + 2 shuffles; PV with shared
// k-order kappa(g,kc,e) = kc*32 + (e>>2)*16 + g*4 + (e&3).
__global__ __launch_bounds__(256, 2) void attn_kernel(const _Float16* __restrict__ Q,
                                                      const _Float16* __restrict__ K,
                                                      const _Float16* __restrict__ Vt,
                                                      _Float16* __restrict__ AO) {
    __shared__ _Float16 Ks[2][64][64];   // [buf][kpos][d]   (chunk-swizzled)
    __shared__ _Float16 Vs[2][64][64];   // [buf][d][kpos]   (chunk-swizzled)

    const int tid = threadIdx.x, wid = tid >> 6, l = tid & 63;
    const int g = l >> 4, li = l & 15;
    const int qt = blockIdx.x, h = blockIdx.y, b = blockIdx.z;

    const _Float16* Qh  = Q  + ((size_t)(b * SEQ) + qt * 128 + wid * 32) * DIM + h * HD;
    const _Float16* Kh  = K  + (size_t)(b * SEQ) * DIM + h * HD;
    const _Float16* Vth = Vt + (size_t)(h * HD) * MROWS + b * SEQ;
    _Float16* AOh = AO + ((size_t)(b * SEQ) + qt * 128 + wid * 32) * DIM + h * HD;

    const int srow   = l >> 3;               // staging row within 8-row chunk
    const int schunk = (l & 7) ^ srow;       // INVERSE-SWIZZLED source chunk
    const int p7 = li & 7;                   // read-side row parity

    // Q fragments: Q[q=nt*16+li][d=dc*32+g*8+e]
    s8h qf[2][2];
#pragma unroll
    for (int nt = 0; nt < 2; ++nt)
#pragma unroll
        for (int dc = 0; dc < 2; ++dc)
            qf[nt][dc] = *(const s8h*)(Qh + (size_t)(nt * 16 + li) * DIM + dc * 32 + g * 8);

    f32x4 o[4][2];                 // O^T[d=mtd*16+g*4+jj][q=nt*16+li]
    float mrun[2], lrun[2];
#pragma unroll
    for (int nt = 0; nt < 2; ++nt) { mrun[nt] = -INFINITY; lrun[nt] = 0.f; }
#pragma unroll
    for (int mtd = 0; mtd < 4; ++mtd)
#pragma unroll
        for (int nt = 0; nt < 2; ++nt) o[mtd][nt] = (f32x4){0.f, 0.f, 0.f, 0.f};

    const float C1 = 0.125f * 1.44269504088896f;   // 1/sqrt(64) * log2(e)

    // prologue: stage tile 0 into buf 0 (wave wid stages rows wid*16..+15)
#pragma unroll
    for (int i = 0; i < 2; ++i) {
        int r = wid * 16 + i * 8;
        gll16(Kh  + (size_t)(r + srow) * DIM   + schunk * 8, &Ks[0][r][0]);
        gll16(Vth + (size_t)(r + srow) * MROWS + schunk * 8, &Vs[0][r][0]);
    }

    for (int kt = 0; kt < NT; ++kt) {
        const int buf = kt & 1;
        __syncthreads();   // drains staging vmcnt; buf ready, buf^1 free

        // stage next tile early: loads fly under QK^T + softmax + PV
        if (kt + 1 < NT) {
#pragma unroll
            for (int i = 0; i < 2; ++i) {
                int r = wid * 16 + i * 8;
                gll16(Kh  + (size_t)((kt + 1) * 64 + r + srow) * DIM + schunk * 8,
                      &Ks[buf ^ 1][r][0]);
                gll16(Vth + (size_t)(r + srow) * MROWS + (kt + 1) * 64 + schunk * 8,
                      &Vs[buf ^ 1][r][0]);
            }
        }

        // ---- S^T = K * Q^T (K frags from LDS, swizzled chunks) ----
        f32x4 st[4][2];
#pragma unroll
        for (int mt = 0; mt < 4; ++mt)
#pragma unroll
            for (int nt = 0; nt < 2; ++nt) st[mt][nt] = (f32x4){0.f, 0.f, 0.f, 0.f};
#pragma unroll
        for (int mt = 0; mt < 4; ++mt) {
            const _Float16* krow = &Ks[buf][mt * 16 + li][0];
            s8h k0 = *(const s8h*)(krow + ((0 + g) ^ p7) * 8);
            s8h k1 = *(const s8h*)(krow + ((4 + g) ^ p7) * 8);
#pragma unroll
            for (int nt = 0; nt < 2; ++nt) {
                st[mt][nt] = mfma16(k0, qf[nt][0], st[mt][nt]);
                st[mt][nt] = mfma16(k1, qf[nt][1], st[mt][nt]);
            }
        }

        // ---- V^T fragments from LDS (swizzled chunks; b64 reads) ----
        // linear byte col0 = kc*64+g*8 -> chunk kc*4+(g>>1), in-chunk (g&1)*8;
        // second half at +32B -> chunk +2.
        s4h va[4][2][2];
#pragma unroll
        for (int mtd = 0; mtd < 4; ++mtd)
#pragma unroll
            for (int kc = 0; kc < 2; ++kc) {
                const _Float16* vrow = &Vs[buf][mtd * 16 + li][0];
                int c0 = kc * 4 + (g >> 1), ofs = (g & 1) * 4;
                va[mtd][kc][0] = *(const s4h*)(vrow + ((c0 + 0) ^ p7) * 8 + ofs);
                va[mtd][kc][1] = *(const s4h*)(vrow + ((c0 + 2) ^ p7) * 8 + ofs);
            }

        // ---- online softmax per q (=nt,li); kpos spread over mt,g,jj ----
#pragma unroll
        for (int nt = 0; nt < 2; ++nt) {
            float tm = st[0][nt][0];
#pragma unroll
            for (int mt = 0; mt < 4; ++mt)
#pragma unroll
                for (int jj = 0; jj < 4; ++jj)
                    if (mt || jj) tm = fmaxf(tm, st[mt][nt][jj]);
            tm = fmaxf(tm, __shfl_xor(tm, 16));
            tm = fmaxf(tm, __shfl_xor(tm, 32));
            float mo = mrun[nt];
            float mn = fmaxf(mo, tm);
            float alpha = ex2((mo - mn) * C1);
            float rs = 0.f;
#pragma unroll
            for (int mt = 0; mt < 4; ++mt)
#pragma unroll
                for (int jj = 0; jj < 4; ++jj) {
                    float p = ex2((st[mt][nt][jj] - mn) * C1);
                    st[mt][nt][jj] = p;
                    rs += p;
                }
            rs += __shfl_xor(rs, 16);
            rs += __shfl_xor(rs, 32);
            lrun[nt] = lrun[nt] * alpha + rs;
            mrun[nt] = mn;
#pragma unroll
            for (int mtd = 0; mtd < 4; ++mtd) {
                o[mtd][nt][0] *= alpha; o[mtd][nt][1] *= alpha;
                o[mtd][nt][2] *= alpha; o[mtd][nt][3] *= alpha;
            }
        }

        // ---- P^T -> f16 B-fragments in k-order kappa ----
        s8h pb[2][2];
#pragma unroll
        for (int nt = 0; nt < 2; ++nt)
#pragma unroll
            for (int kc = 0; kc < 2; ++kc)
#pragma unroll
                for (int e = 0; e < 8; ++e)
                    pb[nt][kc][e] = (_Float16)st[kc * 2 + (e >> 2)][nt][e & 3];

        // ---- O^T += V^T * P^T ----
#pragma unroll
        for (int mtd = 0; mtd < 4; ++mtd)
#pragma unroll
            for (int kc = 0; kc < 2; ++kc) {
                s8h v8;
#pragma unroll
                for (int e = 0; e < 4; ++e) { v8[e] = va[mtd][kc][0][e]; v8[4 + e] = va[mtd][kc][1][e]; }
#pragma unroll
                for (int nt = 0; nt < 2; ++nt)
                    o[mtd][nt] = mfma16(v8, pb[nt][kc], o[mtd][nt]);
            }
    }

    // ---- epilogue: normalize, 8B packed stores ----
#pragma unroll
    for (int nt = 0; nt < 2; ++nt) {
        float inv = 1.0f / lrun[nt];
#pragma unroll
        for (int mtd = 0; mtd < 4; ++mtd) {
            s4h w;
#pragma unroll
            for (int jj = 0; jj < 4; ++jj) w[jj] = (_Float16)(o[mtd][nt][jj] * inv);
            *(s4h*)(AOh + (size_t)(nt * 16 + li) * DIM + mtd * 16 + g * 4) = w;
        }
    }
}

// ---------------- launch ----------------
extern "C" void kernel_launch(void* const* d_in, const int* in_sizes, int n_in,
                              void* d_out, int out_size, void* d_ws, size_t ws_size,
                              hipStream_t stream) {
    const float* x  = (const float*)d_in[0];
    const float* Wq = (const float*)d_in[1];
    const float* Wk = (const float*)d_in[2];
    const float* Wv = (const float*)d_in[3];
    const float* Wo = (const float*)d_in[4];
    float* out = (float*)d_out;

    char* ws = (char*)d_ws;
    _Float16* xh  = (_Float16*)(ws);
    _Float16* Wqh = (_Float16*)(ws + 8388608);
    _Float16* Wkh = (_Float16*)(ws + 10485760);
    _Float16* Wvh = (_Float16*)(ws + 12582912);
    _Float16* Woh = (_Float16*)(ws + 14680064);
    _Float16* Qh  = (_Float16*)(ws + 16777216);
    _Float16* Kh  = (_Float16*)(ws + 25165824);
    _Float16* Vth = (_Float16*)(ws + 33554432);   // V^T [1024][4096]
    _Float16* AOh = (_Float16*)(ws + 41943040);
    float2*   tbl = (float2*)  (ws + 50331648);

    cast_f16_kernel<<<4096, 256, 0, stream>>>(x, Wq, Wk, Wv, Wo, xh, Wqh, Wkh, Wvh, Woh);
    rope_table_kernel<<<256, 256, 0, stream>>>(tbl);
    gemm_qkv_kernel<<<dim3(8, 32, 3), 256, 0, stream>>>(xh, Wqh, Wkh, Wvh, Qh, Kh, Vth);
    rope_f16_kernel<<<2048, 256, 0, stream>>>(Qh, Kh, tbl);
    attn_kernel<<<dim3(16, 16, 2), 256, 0, stream>>>(Qh, Kh, Vth, AOh);
    gemm_out_kernel<<<dim3(8, 32), 256, 0, stream>>>(AOh, Woh, out);
}

// Round 9
// 227.306 us; speedup vs baseline: 2.2223x; 1.0281x over previous
//
#include <hip/hip_runtime.h>

#define DIM   1024
#define NHEAD 16
#define HD    64
#define SEQ   2048
#define BATCH 2
#define MROWS (BATCH * SEQ)   // 4096
#define NT    (SEQ / 64)      // 32 KV tiles

typedef __attribute__((ext_vector_type(8))) _Float16 s8h;   // 8 f16 in 4 VGPRs
typedef __attribute__((ext_vector_type(4))) _Float16 s4h;   // 4 f16 (8B)
typedef __attribute__((ext_vector_type(4))) float f32x4;

typedef const __attribute__((address_space(1))) unsigned GU;
typedef __attribute__((address_space(3))) unsigned LU;

__device__ __forceinline__ void gll16(const void* g, void* l) {
    // async global->LDS, 16B/lane; LDS dest = wave-uniform base + lane*16
    __builtin_amdgcn_global_load_lds((GU*)g, (LU*)l, 16, 0, 0);
}
__device__ __forceinline__ f32x4 mfma16(s8h a, s8h b, f32x4 c) {
    return __builtin_amdgcn_mfma_f32_16x16x32_f16(a, b, c, 0, 0, 0);
}
// 2^x via v_exp_f32. NOTE: not named __exp2f (glibc owns that symbol).
__device__ __forceinline__ float ex2(float x) {
    return __builtin_amdgcn_exp2f(x);
}

// ---------------- fp32 -> fp16 cast: x | Wq | Wk | Wv | Wo ----------------
__global__ __launch_bounds__(256) void cast_f16_kernel(
    const float* __restrict__ x,  const float* __restrict__ wq,
    const float* __restrict__ wk, const float* __restrict__ wv,
    const float* __restrict__ wo,
    _Float16* __restrict__ xh,  _Float16* __restrict__ wqh,
    _Float16* __restrict__ wkh, _Float16* __restrict__ wvh,
    _Float16* __restrict__ woh) {
    int id = blockIdx.x * 256 + threadIdx.x;   // 1,048,576 threads x 8 elems
    const float* src; _Float16* dst; size_t off;
    if (id < 524288) { src = x; dst = xh; off = (size_t)id * 8; }
    else {
        int r = id - 524288, w = r >> 17, o = r & 131071;
        src = (w == 0) ? wq : (w == 1) ? wk : (w == 2) ? wv : wo;
        dst = (w == 0) ? wqh : (w == 1) ? wkh : (w == 2) ? wvh : woh;
        off = (size_t)o * 8;
    }
    float4 v0 = *(const float4*)(src + off);
    float4 v1 = *(const float4*)(src + off + 4);
    s8h y;
    y[0]=(_Float16)v0.x; y[1]=(_Float16)v0.y; y[2]=(_Float16)v0.z; y[3]=(_Float16)v0.w;
    y[4]=(_Float16)v1.x; y[5]=(_Float16)v1.y; y[6]=(_Float16)v1.z; y[7]=(_Float16)v1.w;
    *(s8h*)(dst + off) = y;
}

// ---------------- RoPE cos/sin table [SEQ][32] float2 ----------------
__global__ __launch_bounds__(256) void rope_table_kernel(float2* __restrict__ tbl) {
    int idx = blockIdx.x * 256 + threadIdx.x;     // 65536
    int s = idx >> 5, i = idx & 31;
    float freq = powf(10000.0f, -(float)(2 * i) * (1.0f / 64.0f));
    float ang  = (float)s * freq;
    tbl[idx] = make_float2(cosf(ang), sinf(ang));
}

// ---------------- f16 GEMM NT: C[rb+128][cb+128] = A*B^T, K=DIM -----------
// m97-proven structure: 128x128 tile, BK=64, 4 waves (2x2 of 64x64),
// LINEAR LDS [128][64] staged by global_load_lds.
// ROPE: fused rotation in the epilogue (Q/K projections). Thread holds the
// full head-pair: c = colBase + wc*64 + n*16 + li, pair (i,i+32) <-> (n,n+2).
template <bool F32OUT, bool ROPE>
__device__ __forceinline__ void gemm_core(const _Float16* __restrict__ A,
                                          const _Float16* __restrict__ Bw,
                                          void* __restrict__ C, int ldc,
                                          int rowBase, int colBase,
                                          const float2* __restrict__ tbl) {
    __shared__ _Float16 As[128][64];
    __shared__ _Float16 Bs[128][64];
    const int tid = threadIdx.x, wid = tid >> 6, l = tid & 63;
    const int g = l >> 4, li = l & 15;
    const int wr = wid >> 1, wc = wid & 1;

    f32x4 acc[4][4];
#pragma unroll
    for (int m = 0; m < 4; ++m)
#pragma unroll
        for (int n = 0; n < 4; ++n) acc[m][n] = (f32x4){0.f, 0.f, 0.f, 0.f};

    const int srow = l >> 3;       // row within 8-row chunk
    const int schunk = l & 7;      // 16B chunk within row (LINEAR)

    for (int kt = 0; kt < DIM / 64; ++kt) {
#pragma unroll
        for (int i = 0; i < 4; ++i) {
            int c = wid * 4 + i;
            gll16(A  + (size_t)(rowBase + c * 8 + srow) * DIM + kt * 64 + schunk * 8, &As[c * 8][0]);
            gll16(Bw + (size_t)(colBase + c * 8 + srow) * DIM + kt * 64 + schunk * 8, &Bs[c * 8][0]);
        }
        __syncthreads();
        s8h a[4][2], b[4][2];
#pragma unroll
        for (int m = 0; m < 4; ++m) {
            int row = wr * 64 + m * 16 + li;
            a[m][0] = *(const s8h*)&As[row][g * 8];
            a[m][1] = *(const s8h*)&As[row][32 + g * 8];
        }
#pragma unroll
        for (int n = 0; n < 4; ++n) {
            int col = wc * 64 + n * 16 + li;
            b[n][0] = *(const s8h*)&Bs[col][g * 8];
            b[n][1] = *(const s8h*)&Bs[col][32 + g * 8];
        }
#pragma unroll
        for (int m = 0; m < 4; ++m)
#pragma unroll
            for (int n = 0; n < 4; ++n) {
                acc[m][n] = mfma16(a[m][0], b[n][0], acc[m][n]);
                acc[m][n] = mfma16(a[m][1], b[n][1], acc[m][n]);
            }
        __syncthreads();
    }
#pragma unroll
    for (int m = 0; m < 4; ++m)
#pragma unroll
        for (int j = 0; j < 4; ++j) {
            int r = rowBase + wr * 64 + m * 16 + g * 4 + j;
            if (ROPE) {
                int s = r & (SEQ - 1);
#pragma unroll
                for (int n = 0; n < 2; ++n) {   // freq i = n*16+li (<32)
                    float2 cs = tbl[s * 32 + n * 16 + li];
                    float av = acc[m][n][j], bv = acc[m][n + 2][j];
                    acc[m][n][j]     = av * cs.x - bv * cs.y;
                    acc[m][n + 2][j] = bv * cs.x + av * cs.y;
                }
            }
#pragma unroll
            for (int n = 0; n < 4; ++n) {
                int c = colBase + wc * 64 + n * 16 + li;
                if (F32OUT) ((float*)C)[(size_t)r * ldc + c] = acc[m][n][j];
                else        ((_Float16*)C)[(size_t)r * ldc + c] = (_Float16)acc[m][n][j];
            }
        }
}

// z=0: Q = rope(X Wq^T)  z=1: K = rope(X Wk^T)  z=2: V^T = Wv X^T (ldc=MROWS)
// XCD-aware chunked swizzle (T1): 768 blocks, 96/XCD.
__global__ __launch_bounds__(256) void gemm_qkv_kernel(
    const _Float16* __restrict__ X,
    const _Float16* __restrict__ Wq, const _Float16* __restrict__ Wk,
    const _Float16* __restrict__ Wv,
    _Float16* __restrict__ Q, _Float16* __restrict__ K,
    _Float16* __restrict__ Vt, const float2* __restrict__ tbl) {
    int lin = blockIdx.x + (blockIdx.y << 3) + (blockIdx.z << 8);   // [0,768)
    int swz = (lin & 7) * 96 + (lin >> 3);
    int bx = swz & 7, by = (swz >> 3) & 31, bz = swz >> 8;
    if (bz == 2) {
        gemm_core<false, false>(Wv, X, Vt, MROWS, bx * 128, by * 128, nullptr);
    } else if (bz == 0) {
        gemm_core<false, true>(X, Wq, Q, DIM, by * 128, bx * 128, tbl);
    } else {
        gemm_core<false, true>(X, Wk, K, DIM, by * 128, bx * 128, tbl);
    }
}
__global__ __launch_bounds__(256) void gemm_out_kernel(
    const _Float16* __restrict__ AO, const _Float16* __restrict__ Wo,
    float* __restrict__ OUT) {
    int lin = blockIdx.x + (blockIdx.y << 3);                       // [0,256)
    int swz = (lin & 7) * 32 + (lin >> 3);
    int bx = swz & 7, by = swz >> 3;
    gemm_core<true, false>(AO, Wo, OUT, DIM, by * 128, bx * 128, nullptr);
}

// ---------------- flash attention: LDS-shared K/V + XOR swizzle ------------
// r8 counters: attn latency-bound at 2 blocks/CU (MfmaUtil 18, VALUBusy 44,
// Occ 19.6) -> halve q-rows/block (64), double grid (1024 blocks), 4 blocks/CU
// via launch_bounds(256,4). Same total work, 2x waves to overlap pipes.
// LDS tiles chunk-swizzled (T2, rule #21): linear gll16 dest, source chunk
// (l&7)^(l>>3), read chunk ^ (row&7). XCD swizzle: 128 consecutive blocks
// (4 heads' K/V) per XCD.
__global__ __launch_bounds__(256, 4) void attn_kernel(const _Float16* __restrict__ Q,
                                                      const _Float16* __restrict__ K,
                                                      const _Float16* __restrict__ Vt,
                                                      _Float16* __restrict__ AO) {
    __shared__ _Float16 Ks[2][64][64];   // [buf][kpos][d]   (chunk-swizzled)
    __shared__ _Float16 Vs[2][64][64];   // [buf][d][kpos]   (chunk-swizzled)

    const int tid = threadIdx.x, wid = tid >> 6, l = tid & 63;
    const int g = l >> 4, li = l & 15;
    int lin = blockIdx.x + (blockIdx.y << 5) + (blockIdx.z << 9);   // [0,1024)
    int swz = (lin & 7) * 128 + (lin >> 3);
    const int qt = swz & 31, h = (swz >> 5) & 15, b = swz >> 9;

    const _Float16* Qh  = Q  + ((size_t)(b * SEQ) + qt * 64 + wid * 16) * DIM + h * HD;
    const _Float16* Kh  = K  + (size_t)(b * SEQ) * DIM + h * HD;
    const _Float16* Vth = Vt + (size_t)(h * HD) * MROWS + b * SEQ;
    _Float16* AOh = AO + ((size_t)(b * SEQ) + qt * 64 + wid * 16) * DIM + h * HD;

    const int srow   = l >> 3;               // staging row within 8-row chunk
    const int schunk = (l & 7) ^ srow;       // INVERSE-SWIZZLED source chunk
    const int p7 = li & 7;                   // read-side row parity

    // Q fragments: Q[q=li][d=dc*32+g*8+e]
    s8h qf[2];
#pragma unroll
    for (int dc = 0; dc < 2; ++dc)
        qf[dc] = *(const s8h*)(Qh + (size_t)li * DIM + dc * 32 + g * 8);

    f32x4 o[4];                    // O^T[d=mtd*16+g*4+jj][q=li]
    float mrun = -INFINITY, lrun = 0.f;
#pragma unroll
    for (int mtd = 0; mtd < 4; ++mtd) o[mtd] = (f32x4){0.f, 0.f, 0.f, 0.f};

    const float C1 = 0.125f * 1.44269504088896f;   // 1/sqrt(64) * log2(e)

    // prologue: stage tile 0 into buf 0 (wave wid stages rows wid*16..+15)
#pragma unroll
    for (int i = 0; i < 2; ++i) {
        int r = wid * 16 + i * 8;
        gll16(Kh  + (size_t)(r + srow) * DIM   + schunk * 8, &Ks[0][r][0]);
        gll16(Vth + (size_t)(r + srow) * MROWS + schunk * 8, &Vs[0][r][0]);
    }

    for (int kt = 0; kt < NT; ++kt) {
        const int buf = kt & 1;
        __syncthreads();   // drains staging vmcnt; buf ready, buf^1 free

        // stage next tile early: loads fly under QK^T + softmax + PV
        if (kt + 1 < NT) {
#pragma unroll
            for (int i = 0; i < 2; ++i) {
                int r = wid * 16 + i * 8;
                gll16(Kh  + (size_t)((kt + 1) * 64 + r + srow) * DIM + schunk * 8,
                      &Ks[buf ^ 1][r][0]);
                gll16(Vth + (size_t)(r + srow) * MROWS + (kt + 1) * 64 + schunk * 8,
                      &Vs[buf ^ 1][r][0]);
            }
        }

        // ---- S^T = K * Q^T (K frags from LDS, swizzled chunks) ----
        f32x4 st[4];
#pragma unroll
        for (int mt = 0; mt < 4; ++mt) st[mt] = (f32x4){0.f, 0.f, 0.f, 0.f};
#pragma unroll
        for (int mt = 0; mt < 4; ++mt) {
            const _Float16* krow = &Ks[buf][mt * 16 + li][0];
            s8h k0 = *(const s8h*)(krow + ((0 + g) ^ p7) * 8);
            s8h k1 = *(const s8h*)(krow + ((4 + g) ^ p7) * 8);
            st[mt] = mfma16(k0, qf[0], st[mt]);
            st[mt] = mfma16(k1, qf[1], st[mt]);
        }

        // ---- V^T fragments from LDS (swizzled chunks; b64 reads) ----
        s4h va[4][2][2];
#pragma unroll
        for (int mtd = 0; mtd < 4; ++mtd)
#pragma unroll
            for (int kc = 0; kc < 2; ++kc) {
                const _Float16* vrow = &Vs[buf][mtd * 16 + li][0];
                int c0 = kc * 4 + (g >> 1), ofs = (g & 1) * 4;
                va[mtd][kc][0] = *(const s4h*)(vrow + ((c0 + 0) ^ p7) * 8 + ofs);
                va[mtd][kc][1] = *(const s4h*)(vrow + ((c0 + 2) ^ p7) * 8 + ofs);
            }

        // ---- online softmax for q-col li; kpos spread over mt,g,jj ----
        {
            float tm = st[0][0];
#pragma unroll
            for (int mt = 0; mt < 4; ++mt)
#pragma unroll
                for (int jj = 0; jj < 4; ++jj)
                    if (mt || jj) tm = fmaxf(tm, st[mt][jj]);
            tm = fmaxf(tm, __shfl_xor(tm, 16));
            tm = fmaxf(tm, __shfl_xor(tm, 32));
            float mo = mrun;
            float mn = fmaxf(mo, tm);
            float alpha = ex2((mo - mn) * C1);
            float rs = 0.f;
#pragma unroll
            for (int mt = 0; mt < 4; ++mt)
#pragma unroll
                for (int jj = 0; jj < 4; ++jj) {
                    float p = ex2((st[mt][jj] - mn) * C1);
                    st[mt][jj] = p;
                    rs += p;
                }
            rs += __shfl_xor(rs, 16);
            rs += __shfl_xor(rs, 32);
            lrun = lrun * alpha + rs;
            mrun = mn;
#pragma unroll
            for (int mtd = 0; mtd < 4; ++mtd) {
                o[mtd][0] *= alpha; o[mtd][1] *= alpha;
                o[mtd][2] *= alpha; o[mtd][3] *= alpha;
            }
        }

        // ---- P^T -> f16 B-fragments in k-order kappa ----
        s8h pb[2];
#pragma unroll
        for (int kc = 0; kc < 2; ++kc)
#pragma unroll
            for (int e = 0; e < 8; ++e)
                pb[kc][e] = (_Float16)st[kc * 2 + (e >> 2)][e & 3];

        // ---- O^T += V^T * P^T ----
#pragma unroll
        for (int mtd = 0; mtd < 4; ++mtd)
#pragma unroll
            for (int kc = 0; kc < 2; ++kc) {
                s8h v8;
#pragma unroll
                for (int e = 0; e < 4; ++e) { v8[e] = va[mtd][kc][0][e]; v8[4 + e] = va[mtd][kc][1][e]; }
                o[mtd] = mfma16(v8, pb[kc], o[mtd]);
            }
    }

    // ---- epilogue: normalize, 8B packed stores ----
    {
        float inv = 1.0f / lrun;
#pragma unroll
        for (int mtd = 0; mtd < 4; ++mtd) {
            s4h w;
#pragma unroll
            for (int jj = 0; jj < 4; ++jj) w[jj] = (_Float16)(o[mtd][jj] * inv);
            *(s4h*)(AOh + (size_t)li * DIM + mtd * 16 + g * 4) = w;
        }
    }
}

// ---------------- launch ----------------
extern "C" void kernel_launch(void* const* d_in, const int* in_sizes, int n_in,
                              void* d_out, int out_size, void* d_ws, size_t ws_size,
                              hipStream_t stream) {
    const float* x  = (const float*)d_in[0];
    const float* Wq = (const float*)d_in[1];
    const float* Wk = (const float*)d_in[2];
    const float* Wv = (const float*)d_in[3];
    const float* Wo = (const float*)d_in[4];
    float* out = (float*)d_out;

    char* ws = (char*)d_ws;
    _Float16* xh  = (_Float16*)(ws);
    _Float16* Wqh = (_Float16*)(ws + 8388608);
    _Float16* Wkh = (_Float16*)(ws + 10485760);
    _Float16* Wvh = (_Float16*)(ws + 12582912);
    _Float16* Woh = (_Float16*)(ws + 14680064);
    _Float16* Qh  = (_Float16*)(ws + 16777216);
    _Float16* Kh  = (_Float16*)(ws + 25165824);
    _Float16* Vth = (_Float16*)(ws + 33554432);   // V^T [1024][4096]
    _Float16* AOh = (_Float16*)(ws + 41943040);
    float2*   tbl = (float2*)  (ws + 50331648);

    cast_f16_kernel<<<4096, 256, 0, stream>>>(x, Wq, Wk, Wv, Wo, xh, Wqh, Wkh, Wvh, Woh);
    rope_table_kernel<<<256, 256, 0, stream>>>(tbl);
    gemm_qkv_kernel<<<dim3(8, 32, 3), 256, 0, stream>>>(xh, Wqh, Wkh, Wvh, Qh, Kh, Vth, tbl);
    attn_kernel<<<dim3(32, 16, 2), 256, 0, stream>>>(Qh, Kh, Vth, AOh);
    gemm_out_kernel<<<dim3(8, 32), 256, 0, stream>>>(AOh, Woh, out);
}

// Round 11
// 222.419 us; speedup vs baseline: 2.2712x; 1.0220x over previous
//
#include <hip/hip_runtime.h>

#define DIM   1024
#define NHEAD 16
#define HD    64
#define SEQ   2048
#define BATCH 2
#define MROWS (BATCH * SEQ)   // 4096
#define NT    (SEQ / 64)      // 32 KV tiles

typedef __attribute__((ext_vector_type(8))) _Float16 s8h;   // 8 f16 in 4 VGPRs
typedef __attribute__((ext_vector_type(4))) _Float16 s4h;   // 4 f16 (8B)
typedef __attribute__((ext_vector_type(4))) float f32x4;

typedef const __attribute__((address_space(1))) unsigned GU;
typedef __attribute__((address_space(3))) unsigned LU;

__device__ __forceinline__ void gll16(const void* g, void* l) {
    // async global->LDS, 16B/lane; LDS dest = wave-uniform base + lane*16
    __builtin_amdgcn_global_load_lds((GU*)g, (LU*)l, 16, 0, 0);
}
__device__ __forceinline__ f32x4 mfma16(s8h a, s8h b, f32x4 c) {
    return __builtin_amdgcn_mfma_f32_16x16x32_f16(a, b, c, 0, 0, 0);
}
// 2^x via v_exp_f32. NOTE: not named __exp2f (glibc owns that symbol).
__device__ __forceinline__ float ex2(float x) {
    return __builtin_amdgcn_exp2f(x);
}

// -------- prep: fp32->fp16 cast of x|Wq|Wk|Wv|Wo  +  RoPE table ------------
__global__ __launch_bounds__(256) void prep_kernel(
    const float* __restrict__ x,  const float* __restrict__ wq,
    const float* __restrict__ wk, const float* __restrict__ wv,
    const float* __restrict__ wo,
    _Float16* __restrict__ xh,  _Float16* __restrict__ wqh,
    _Float16* __restrict__ wkh, _Float16* __restrict__ wvh,
    _Float16* __restrict__ woh, float2* __restrict__ tbl) {
    if (blockIdx.x >= 4096) {   // RoPE table: [SEQ][32] float2
        int idx = (blockIdx.x - 4096) * 256 + threadIdx.x;   // 65536
        int s = idx >> 5, i = idx & 31;
        float freq = powf(10000.0f, -(float)(2 * i) * (1.0f / 64.0f));
        float ang  = (float)s * freq;
        tbl[idx] = make_float2(cosf(ang), sinf(ang));
        return;
    }
    int id = blockIdx.x * 256 + threadIdx.x;   // 1,048,576 threads x 8 elems
    const float* src; _Float16* dst; size_t off;
    if (id < 524288) { src = x; dst = xh; off = (size_t)id * 8; }
    else {
        int r = id - 524288, w = r >> 17, o = r & 131071;
        src = (w == 0) ? wq : (w == 1) ? wk : (w == 2) ? wv : wo;
        dst = (w == 0) ? wqh : (w == 1) ? wkh : (w == 2) ? wvh : woh;
        off = (size_t)o * 8;
    }
    float4 v0 = *(const float4*)(src + off);
    float4 v1 = *(const float4*)(src + off + 4);
    s8h y;
    y[0]=(_Float16)v0.x; y[1]=(_Float16)v0.y; y[2]=(_Float16)v0.z; y[3]=(_Float16)v0.w;
    y[4]=(_Float16)v1.x; y[5]=(_Float16)v1.y; y[6]=(_Float16)v1.z; y[7]=(_Float16)v1.w;
    *(s8h*)(dst + off) = y;
}

// ---------------- f16 GEMM NT: C[rb+128][cb+128] = A*B^T, K=DIM -----------
// m97-proven structure: 128x128 tile, BK=64, 4 waves (2x2 of 64x64),
// LINEAR LDS [128][64] staged by global_load_lds.
// ROPE: fused rotation in the epilogue (Q/K projections). Thread holds the
// full head-pair: c = colBase + wc*64 + n*16 + li, pair (i,i+32) <-> (n,n+2).
template <bool F32OUT, bool ROPE>
__device__ __forceinline__ void gemm_core(const _Float16* __restrict__ A,
                                          const _Float16* __restrict__ Bw,
                                          void* __restrict__ C, int ldc,
                                          int rowBase, int colBase,
                                          const float2* __restrict__ tbl) {
    __shared__ _Float16 As[128][64];
    __shared__ _Float16 Bs[128][64];
    const int tid = threadIdx.x, wid = tid >> 6, l = tid & 63;
    const int g = l >> 4, li = l & 15;
    const int wr = wid >> 1, wc = wid & 1;

    f32x4 acc[4][4];
#pragma unroll
    for (int m = 0; m < 4; ++m)
#pragma unroll
        for (int n = 0; n < 4; ++n) acc[m][n] = (f32x4){0.f, 0.f, 0.f, 0.f};

    const int srow = l >> 3;       // row within 8-row chunk
    const int schunk = l & 7;      // 16B chunk within row (LINEAR)

    for (int kt = 0; kt < DIM / 64; ++kt) {
#pragma unroll
        for (int i = 0; i < 4; ++i) {
            int c = wid * 4 + i;
            gll16(A  + (size_t)(rowBase + c * 8 + srow) * DIM + kt * 64 + schunk * 8, &As[c * 8][0]);
            gll16(Bw + (size_t)(colBase + c * 8 + srow) * DIM + kt * 64 + schunk * 8, &Bs[c * 8][0]);
        }
        __syncthreads();
        s8h a[4][2], b[4][2];
#pragma unroll
        for (int m = 0; m < 4; ++m) {
            int row = wr * 64 + m * 16 + li;
            a[m][0] = *(const s8h*)&As[row][g * 8];
            a[m][1] = *(const s8h*)&As[row][32 + g * 8];
        }
#pragma unroll
        for (int n = 0; n < 4; ++n) {
            int col = wc * 64 + n * 16 + li;
            b[n][0] = *(const s8h*)&Bs[col][g * 8];
            b[n][1] = *(const s8h*)&Bs[col][32 + g * 8];
        }
#pragma unroll
        for (int m = 0; m < 4; ++m)
#pragma unroll
            for (int n = 0; n < 4; ++n) {
                acc[m][n] = mfma16(a[m][0], b[n][0], acc[m][n]);
                acc[m][n] = mfma16(a[m][1], b[n][1], acc[m][n]);
            }
        __syncthreads();
    }
#pragma unroll
    for (int m = 0; m < 4; ++m)
#pragma unroll
        for (int j = 0; j < 4; ++j) {
            int r = rowBase + wr * 64 + m * 16 + g * 4 + j;
            if (ROPE) {
                int s = r & (SEQ - 1);
#pragma unroll
                for (int n = 0; n < 2; ++n) {   // freq i = n*16+li (<32)
                    float2 cs = tbl[s * 32 + n * 16 + li];
                    float av = acc[m][n][j], bv = acc[m][n + 2][j];
                    acc[m][n][j]     = av * cs.x - bv * cs.y;
                    acc[m][n + 2][j] = bv * cs.x + av * cs.y;
                }
            }
#pragma unroll
            for (int n = 0; n < 4; ++n) {
                int c = colBase + wc * 64 + n * 16 + li;
                if (F32OUT) ((float*)C)[(size_t)r * ldc + c] = acc[m][n][j];
                else        ((_Float16*)C)[(size_t)r * ldc + c] = (_Float16)acc[m][n][j];
            }
        }
}

// z=0: Q = rope(X Wq^T)  z=1: K = rope(X Wk^T)  z=2: V^T = Wv X^T (ldc=MROWS)
// XCD-aware chunked swizzle (T1): 768 blocks, 96/XCD.
__global__ __launch_bounds__(256) void gemm_qkv_kernel(
    const _Float16* __restrict__ X,
    const _Float16* __restrict__ Wq, const _Float16* __restrict__ Wk,
    const _Float16* __restrict__ Wv,
    _Float16* __restrict__ Q, _Float16* __restrict__ K,
    _Float16* __restrict__ Vt, const float2* __restrict__ tbl) {
    int lin = blockIdx.x + (blockIdx.y << 3) + (blockIdx.z << 8);   // [0,768)
    int swz = (lin & 7) * 96 + (lin >> 3);
    int bx = swz & 7, by = (swz >> 3) & 31, bz = swz >> 8;
    if (bz == 2) {
        gemm_core<false, false>(Wv, X, Vt, MROWS, bx * 128, by * 128, nullptr);
    } else if (bz == 0) {
        gemm_core<false, true>(X, Wq, Q, DIM, by * 128, bx * 128, tbl);
    } else {
        gemm_core<false, true>(X, Wk, K, DIM, by * 128, bx * 128, tbl);
    }
}
__global__ __launch_bounds__(256) void gemm_out_kernel(
    const _Float16* __restrict__ AO, const _Float16* __restrict__ Wo,
    float* __restrict__ OUT) {
    int lin = blockIdx.x + (blockIdx.y << 3);                       // [0,256)
    int swz = (lin & 7) * 32 + (lin >> 3);
    int bx = swz & 7, by = swz >> 3;
    gemm_core<true, false>(AO, Wo, OUT, DIM, by * 128, bx * 128, nullptr);
}

// ---------------- flash attention: LDS-shared K/V + XOR swizzle ------------
// r9 lesson: per-wave K/V LDS-read work is PER-TILE, independent of q-rows
// owned -> 32 q/wave (r8 geometry) amortizes 2x better than 16 q/wave; the
// occupancy gain of smaller blocks doesn't pay for the duplicated reads.
// Grid 512 (16,16,2), 2 blocks/CU; XCD swizzle kept (FETCH 69.7->12.3 MB).
// T13 defer-max: skip alpha/rescale when __all(tm <= mo + 8/C1) — P bounded
// by 2^8, f16/f32 accum safe (HK THR=8).
__global__ __launch_bounds__(256, 2) void attn_kernel(const _Float16* __restrict__ Q,
                                                      const _Float16* __restrict__ K,
                                                      const _Float16* __restrict__ Vt,
                                                      _Float16* __restrict__ AO) {
    __shared__ _Float16 Ks[2][64][64];   // [buf][kpos][d]   (chunk-swizzled)
    __shared__ _Float16 Vs[2][64][64];   // [buf][d][kpos]   (chunk-swizzled)

    const int tid = threadIdx.x, wid = tid >> 6, l = tid & 63;
    const int g = l >> 4, li = l & 15;
    int lin = blockIdx.x + (blockIdx.y << 4) + (blockIdx.z << 8);   // [0,512)
    int swz = (lin & 7) * 64 + (lin >> 3);
    const int qt = swz & 15, h = (swz >> 4) & 15, b = swz >> 8;

    const _Float16* Qh  = Q  + ((size_t)(b * SEQ) + qt * 128 + wid * 32) * DIM + h * HD;
    const _Float16* Kh  = K  + (size_t)(b * SEQ) * DIM + h * HD;
    const _Float16* Vth = Vt + (size_t)(h * HD) * MROWS + b * SEQ;
    _Float16* AOh = AO + ((size_t)(b * SEQ) + qt * 128 + wid * 32) * DIM + h * HD;

    const int srow   = l >> 3;               // staging row within 8-row chunk
    const int schunk = (l & 7) ^ srow;       // INVERSE-SWIZZLED source chunk
    const int p7 = li & 7;                   // read-side row parity

    // Q fragments: Q[q=nt*16+li][d=dc*32+g*8+e]
    s8h qf[2][2];
#pragma unroll
    for (int nt = 0; nt < 2; ++nt)
#pragma unroll
        for (int dc = 0; dc < 2; ++dc)
            qf[nt][dc] = *(const s8h*)(Qh + (size_t)(nt * 16 + li) * DIM + dc * 32 + g * 8);

    f32x4 o[4][2];                 // O^T[d=mtd*16+g*4+jj][q=nt*16+li]
    float mrun[2], lrun[2];
#pragma unroll
    for (int nt = 0; nt < 2; ++nt) { mrun[nt] = -INFINITY; lrun[nt] = 0.f; }
#pragma unroll
    for (int mtd = 0; mtd < 4; ++mtd)
#pragma unroll
        for (int nt = 0; nt < 2; ++nt) o[mtd][nt] = (f32x4){0.f, 0.f, 0.f, 0.f};

    const float C1 = 0.125f * 1.44269504088896f;   // 1/sqrt(64) * log2(e)
    const float DTHR = 8.0f / C1;                  // defer-max threshold (raw)

    // prologue: stage tile 0 into buf 0 (wave wid stages rows wid*16..+15)
#pragma unroll
    for (int i = 0; i < 2; ++i) {
        int r = wid * 16 + i * 8;
        gll16(Kh  + (size_t)(r + srow) * DIM   + schunk * 8, &Ks[0][r][0]);
        gll16(Vth + (size_t)(r + srow) * MROWS + schunk * 8, &Vs[0][r][0]);
    }

    for (int kt = 0; kt < NT; ++kt) {
        const int buf = kt & 1;
        __syncthreads();   // drains staging vmcnt; buf ready, buf^1 free

        // stage next tile early: loads fly under QK^T + softmax + PV
        if (kt + 1 < NT) {
#pragma unroll
            for (int i = 0; i < 2; ++i) {
                int r = wid * 16 + i * 8;
                gll16(Kh  + (size_t)((kt + 1) * 64 + r + srow) * DIM + schunk * 8,
                      &Ks[buf ^ 1][r][0]);
                gll16(Vth + (size_t)(r + srow) * MROWS + (kt + 1) * 64 + schunk * 8,
                      &Vs[buf ^ 1][r][0]);
            }
        }

        // ---- S^T = K * Q^T (K frags from LDS, swizzled chunks) ----
        f32x4 st[4][2];
#pragma unroll
        for (int mt = 0; mt < 4; ++mt)
#pragma unroll
            for (int nt = 0; nt < 2; ++nt) st[mt][nt] = (f32x4){0.f, 0.f, 0.f, 0.f};
#pragma unroll
        for (int mt = 0; mt < 4; ++mt) {
            const _Float16* krow = &Ks[buf][mt * 16 + li][0];
            s8h k0 = *(const s8h*)(krow + ((0 + g) ^ p7) * 8);
            s8h k1 = *(const s8h*)(krow + ((4 + g) ^ p7) * 8);
#pragma unroll
            for (int nt = 0; nt < 2; ++nt) {
                st[mt][nt] = mfma16(k0, qf[nt][0], st[mt][nt]);
                st[mt][nt] = mfma16(k1, qf[nt][1], st[mt][nt]);
            }
        }

        // ---- V^T fragments from LDS (swizzled chunks; b64 reads) ----
        s4h va[4][2][2];
#pragma unroll
        for (int mtd = 0; mtd < 4; ++mtd)
#pragma unroll
            for (int kc = 0; kc < 2; ++kc) {
                const _Float16* vrow = &Vs[buf][mtd * 16 + li][0];
                int c0 = kc * 4 + (g >> 1), ofs = (g & 1) * 4;
                va[mtd][kc][0] = *(const s4h*)(vrow + ((c0 + 0) ^ p7) * 8 + ofs);
                va[mtd][kc][1] = *(const s4h*)(vrow + ((c0 + 2) ^ p7) * 8 + ofs);
            }

        // ---- online softmax per q (=nt,li), defer-max (T13) ----
#pragma unroll
        for (int nt = 0; nt < 2; ++nt) {
            // tree max over 16 in-lane scores
            float t0 = fmaxf(fmaxf(st[0][nt][0], st[0][nt][1]), fmaxf(st[0][nt][2], st[0][nt][3]));
            float t1 = fmaxf(fmaxf(st[1][nt][0], st[1][nt][1]), fmaxf(st[1][nt][2], st[1][nt][3]));
            float t2 = fmaxf(fmaxf(st[2][nt][0], st[2][nt][1]), fmaxf(st[2][nt][2], st[2][nt][3]));
            float t3 = fmaxf(fmaxf(st[3][nt][0], st[3][nt][1]), fmaxf(st[3][nt][2], st[3][nt][3]));
            float tm = fmaxf(fmaxf(t0, t1), fmaxf(t2, t3));
            tm = fmaxf(tm, __shfl_xor(tm, 16));
            tm = fmaxf(tm, __shfl_xor(tm, 32));
            float mo = mrun[nt];
            if (!__all(tm <= mo + DTHR)) {   // rescale only when max grew a lot
                float mn = fmaxf(mo, tm);
                float alpha = ex2((mo - mn) * C1);
                lrun[nt] *= alpha;
                mrun[nt] = mn;
#pragma unroll
                for (int mtd = 0; mtd < 4; ++mtd) {
                    o[mtd][nt][0] *= alpha; o[mtd][nt][1] *= alpha;
                    o[mtd][nt][2] *= alpha; o[mtd][nt][3] *= alpha;
                }
            }
            float mnow = mrun[nt];
            float rs = 0.f;
#pragma unroll
            for (int mt = 0; mt < 4; ++mt)
#pragma unroll
                for (int jj = 0; jj < 4; ++jj) {
                    float p = ex2((st[mt][nt][jj] - mnow) * C1);
                    st[mt][nt][jj] = p;
                    rs += p;
                }
            rs += __shfl_xor(rs, 16);
            rs += __shfl_xor(rs, 32);
            lrun[nt] += rs;
        }

        // ---- P^T -> f16 B-fragments in k-order kappa ----
        s8h pb[2][2];
#pragma unroll
        for (int nt = 0; nt < 2; ++nt)
#pragma unroll
            for (int kc = 0; kc < 2; ++kc)
#pragma unroll
                for (int e = 0; e < 8; ++e)
                    pb[nt][kc][e] = (_Float16)st[kc * 2 + (e >> 2)][nt][e & 3];

        // ---- O^T += V^T * P^T ----
#pragma unroll
        for (int mtd = 0; mtd < 4; ++mtd)
#pragma unroll
            for (int kc = 0; kc < 2; ++kc) {
                s8h v8;
#pragma unroll
                for (int e = 0; e < 4; ++e) { v8[e] = va[mtd][kc][0][e]; v8[4 + e] = va[mtd][kc][1][e]; }
#pragma unroll
                for (int nt = 0; nt < 2; ++nt)
                    o[mtd][nt] = mfma16(v8, pb[nt][kc], o[mtd][nt]);
            }
    }

    // ---- epilogue: normalize, 8B packed stores ----
#pragma unroll
    for (int nt = 0; nt < 2; ++nt) {
        float inv = 1.0f / lrun[nt];
#pragma unroll
        for (int mtd = 0; mtd < 4; ++mtd) {
            s4h w;
#pragma unroll
            for (int jj = 0; jj < 4; ++jj) w[jj] = (_Float16)(o[mtd][nt][jj] * inv);
            *(s4h*)(AOh + (size_t)(nt * 16 + li) * DIM + mtd * 16 + g * 4) = w;
        }
    }
}

// ---------------- launch ----------------
extern "C" void kernel_launch(void* const* d_in, const int* in_sizes, int n_in,
                              void* d_out, int out_size, void* d_ws, size_t ws_size,
                              hipStream_t stream) {
    const float* x  = (const float*)d_in[0];
    const float* Wq = (const float*)d_in[1];
    const float* Wk = (const float*)d_in[2];
    const float* Wv = (const float*)d_in[3];
    const float* Wo = (const float*)d_in[4];
    float* out = (float*)d_out;

    char* ws = (char*)d_ws;
    _Float16* xh  = (_Float16*)(ws);
    _Float16* Wqh = (_Float16*)(ws + 8388608);
    _Float16* Wkh = (_Float16*)(ws + 10485760);
    _Float16* Wvh = (_Float16*)(ws + 12582912);
    _Float16* Woh = (_Float16*)(ws + 14680064);
    _Float16* Qh  = (_Float16*)(ws + 16777216);
    _Float16* Kh  = (_Float16*)(ws + 25165824);
    _Float16* Vth = (_Float16*)(ws + 33554432);   // V^T [1024][4096]
    _Float16* AOh = (_Float16*)(ws + 41943040);
    float2*   tbl = (float2*)  (ws + 50331648);

    prep_kernel<<<4352, 256, 0, stream>>>(x, Wq, Wk, Wv, Wo, xh, Wqh, Wkh, Wvh, Woh, tbl);
    gemm_qkv_kernel<<<dim3(8, 32, 3), 256, 0, stream>>>(xh, Wqh, Wkh, Wvh, Qh, Kh, Vth, tbl);
    attn_kernel<<<dim3(16, 16, 2), 256, 0, stream>>>(Qh, Kh, Vth, AOh);
    gemm_out_kernel<<<dim3(8, 32), 256, 0, stream>>>(AOh, Woh, out);
}